// Round 4
// baseline (1344.326 us; speedup 1.0000x reference)
//
#include <hip/hip_runtime.h>

#define IMG 512
#define HW (IMG * IMG)
#define NB 32
#define NIMG 64
#define BAND 16
#define NBAND (IMG / BAND)              // 32 bands per image
#define NSTG 10                         // ALL iterations fused in one launch
#define HALO (2 * NSTG)                 // 20
#define NSTEP ((BAND + 2 * HALO) / 2)   // 28 row-pair steps
#define INF __builtin_inff()

// DPP whole-wave shift-by-1 (CDNA keeps Vega wave_shl/shr DPP controls).
// wave_shr1: lane i gets lane i-1's value; lane 0 gets `ident`.
static __device__ __forceinline__ float dpp_from_prev(float v, float ident) {
    return __int_as_float(__builtin_amdgcn_update_dpp(
        __float_as_int(ident), __float_as_int(v), 0x138, 0xF, 0xF, false));
}
// wave_shl1: lane i gets lane i+1's value; lane 63 gets `ident`.
static __device__ __forceinline__ float dpp_from_next(float v, float ident) {
    return __int_as_float(__builtin_amdgcn_update_dpp(
        __float_as_int(ident), __float_as_int(v), 0x130, 0xF, 0xF, false));
}

// One lane owns 8 contiguous columns: a = cols[8l..8l+3], b = cols[8l+4..8l+7].
struct Row { float4 a, b; };

static __device__ __forceinline__ float min3f(float a, float b, float c) { return fminf(fminf(a, b), c); }
static __device__ __forceinline__ float max3f(float a, float b, float c) { return fmaxf(fmaxf(a, b), c); }

static __device__ __forceinline__ Row splat(float v) {
    Row r;
    r.a = make_float4(v, v, v, v);
    r.b = make_float4(v, v, v, v);
    return r;
}

static __device__ __forceinline__ Row rmin3(const Row& x, const Row& y, const Row& z) {
    Row o;
    const float* px = (const float*)&x;
    const float* py = (const float*)&y;
    const float* pz = (const float*)&z;
    float* po = (float*)&o;
#pragma unroll
    for (int i = 0; i < 8; ++i) po[i] = min3f(px[i], py[i], pz[i]);
    return o;
}

static __device__ __forceinline__ Row rmax3(const Row& x, const Row& y, const Row& z) {
    Row o;
    const float* px = (const float*)&x;
    const float* py = (const float*)&y;
    const float* pz = (const float*)&z;
    float* po = (float*)&o;
#pragma unroll
    for (int i = 0; i < 8; ++i) po[i] = max3f(px[i], py[i], pz[i]);
    return o;
}

// Horizontal 3-min across the 512-wide row. Lane-edge neighbors via DPP
// wave shifts; image edges get +inf identity for free from bound_ctrl.
static __device__ __forceinline__ Row hmin3(const Row& v) {
    float shl = dpp_from_prev(v.b.w, INF);
    float shr = dpp_from_next(v.a.x, INF);
    Row o;
    o.a.x = min3f(shl,   v.a.x, v.a.y);
    o.a.y = min3f(v.a.x, v.a.y, v.a.z);
    o.a.z = min3f(v.a.y, v.a.z, v.a.w);
    o.a.w = min3f(v.a.z, v.a.w, v.b.x);
    o.b.x = min3f(v.a.w, v.b.x, v.b.y);
    o.b.y = min3f(v.b.x, v.b.y, v.b.z);
    o.b.z = min3f(v.b.y, v.b.z, v.b.w);
    o.b.w = min3f(v.b.z, v.b.w, shr);
    return o;
}

static __device__ __forceinline__ Row hmax3(const Row& v) {
    float shl = dpp_from_prev(v.b.w, -INF);
    float shr = dpp_from_next(v.a.x, -INF);
    Row o;
    o.a.x = max3f(shl,   v.a.x, v.a.y);
    o.a.y = max3f(v.a.x, v.a.y, v.a.z);
    o.a.z = max3f(v.a.y, v.a.z, v.a.w);
    o.a.w = max3f(v.a.z, v.a.w, v.b.x);
    o.b.x = max3f(v.a.w, v.b.x, v.b.y);
    o.b.y = max3f(v.b.x, v.b.y, v.b.z);
    o.b.z = max3f(v.b.y, v.b.z, v.b.w);
    o.b.w = max3f(v.b.z, v.b.w, shr);
    return o;
}

// out = relu(x - relu(mp - mn)). For x >= 0 on every consumed output this is
// bit-exactly med3(0, x, x - (mp - mn)): 3 ops/pixel instead of 4.
// (Verified bit-exact on-harness in rounds 2 and 3, absmax 0.0.)
static __device__ __forceinline__ Row relu_out(const Row& x, const Row& mp, const Row& mn) {
    Row o;
    const float* px = (const float*)&x;
    const float* pp = (const float*)&mp;
    const float* pm = (const float*)&mn;
    float* po = (float*)&o;
#pragma unroll
    for (int i = 0; i < 8; ++i) {
        float d = pp[i] - pm[i];
        po[i] = __builtin_amdgcn_fmed3f(0.f, px[i], px[i] - d);
    }
    return o;
}

static __device__ __forceinline__ Row load_row(const float* __restrict__ p, int r, int lane) {
    if ((unsigned)r >= IMG) return splat(INF);   // uniform scalar branch
    const float4* q = (const float4*)(p + (size_t)r * IMG + lane * 8);
    Row o;
    o.a = q[0];
    o.b = q[1];
    return o;
}

// Row-paired skeletonize stage step (round-0 verified structure).
// Entry state: x[0]=x[t-2], x[1]=x[t-1], mn[0]=mn[t-3], mn[1]=mn[t-2].
// Inputs in0=x[t], in1=x[t+1]. On exit in0/in1 hold this stage's outputs for
// rows (t-2, t-1), state advanced by 2 rows. Rotation is pure renaming.
// EDGE masks are unconditional: uniform scalar branches, ~3% issue cost, and
// they make out-of-image semantics exact for EVERY band (at HALO=20, bands 1
// and 30 also touch rows outside the image, not just bands 0 and 31).
static __device__ __forceinline__ void step2(Row (&x)[2], Row (&mn)[2],
                                             Row& in0, Row& in1, int t) {
    Row vmin0 = rmin3(x[0], x[1], in0);      // centered row t-1
    Row vmin1 = rmin3(x[1], in0, in1);       // centered row t
    Row mna = hmin3(vmin0);                  // mn[t-1]
    Row mnb = hmin3(vmin1);                  // mn[t]
    if ((unsigned)(t - 1) >= IMG) mna = splat(-INF);   // dilate pad = -inf
    if ((unsigned)t >= IMG) mnb = splat(-INF);
    Row vmax0 = rmax3(mn[0], mn[1], mna);    // centered t-2
    Row vmax1 = rmax3(mn[1], mna, mnb);      // centered t-1
    Row mp0 = hmax3(vmax0);
    Row mp1 = hmax3(vmax1);
    Row out0 = relu_out(x[0], mp0, mn[1]);   // out row t-2
    Row out1 = relu_out(x[1], mp1, mna);     // out row t-1
    if ((unsigned)(t - 2) >= IMG) out0 = splat(INF);   // erode pad = +inf
    if ((unsigned)(t - 1) >= IMG) out1 = splat(INF);
    x[0] = in0;  x[1] = in1;
    mn[0] = mna; mn[1] = mnb;
    in0 = out0;  in1 = out1;
}

// All 10 skeletonize iterations over one 16-row band, fused with the
// prod/val reduction. #pragma unroll 1 on the k-loop is deliberate: full
// unroll lets the scheduler hoist all row loads, exploding register pressure
// into scratch spill (round-2 post-mortem: 199 MB of spill writes).
static __device__ __forceinline__ void run10(const float* __restrict__ src,
                                             const float* __restrict__ wp,
                                             int B, int lane,
                                             float& s_prod, float& s_val) {
    Row x[NSTG][2], mn[NSTG][2];
#pragma unroll
    for (int j = 0; j < NSTG; ++j) {
        x[j][0] = splat(INF);   x[j][1] = splat(INF);
        mn[j][0] = splat(-INF); mn[j][1] = splat(-INF);
    }
    Row pre0 = load_row(src, B - HALO, lane);
    Row pre1 = load_row(src, B - HALO + 1, lane);
#pragma unroll 1
    for (int k = 0; k < NSTEP; ++k) {
        const int t = B - HALO + 2 * k;
        Row in0 = pre0, in1 = pre1;
        const int tp = (k + 1 < NSTEP) ? t + 2 : -1;
        pre0 = load_row(src, tp, lane);
        pre1 = load_row(src, tp + 1, lane);
        const int v = t - HALO;              // final-stage out row pair (v, v+1)
        const bool inband = (unsigned)(v - B) < BAND;
        // Issue weight loads before the 10-stage chain; ~3.8k cycles of VALU
        // cover their latency completely.
        Row w0, w1;
        if (inband) {
            const float4* q0 = (const float4*)(wp + (size_t)v * IMG + lane * 8);
            w0.a = q0[0]; w0.b = q0[1];
            const float4* q1 = (const float4*)(wp + (size_t)(v + 1) * IMG + lane * 8);
            w1.a = q1[0]; w1.b = q1[1];
        }
#pragma unroll
        for (int j = 0; j < NSTG; ++j)
            step2(x[j], mn[j], in0, in1, t - 2 * j);
        if (inband) {
            const float* p0 = (const float*)&in0;
            const float* p1 = (const float*)&in1;
            const float* q0 = (const float*)&w0;
            const float* q1 = (const float*)&w1;
#pragma unroll
            for (int i = 0; i < 8; ++i) {
                s_prod += p0[i] * q0[i] + p1[i] * q1[i];
                s_val += p0[i] + p1[i];
            }
        }
    }
}

// Single fused launch: skeletonize(10 iters) + masked reduction, no
// intermediate buffer traffic at all.
__global__ __launch_bounds__(64, 2) void skel10(const float* __restrict__ yp,
                                                const float* __restrict__ yt,
                                                double* __restrict__ acc) {
    const int blk = blockIdx.x;
    const int img = blk >> 5, band = blk & (NBAND - 1);
    // skel(pred) pairs with y_true c1; skel(true) pairs with y_pred c1.
    const float* src = (img < NB) ? yp + (size_t)(2 * img + 1) * HW
                                  : yt + (size_t)(2 * (img - NB) + 1) * HW;
    const float* w = (img < NB) ? yt + (size_t)(2 * img + 1) * HW
                                : yp + (size_t)(2 * (img - NB) + 1) * HW;
    const int lane = threadIdx.x;
    const int B = band * BAND;

    float s_prod = 0.f, s_val = 0.f;
    run10(src, w, B, lane, s_prod, s_val);

#pragma unroll
    for (int off = 32; off; off >>= 1) {
        s_prod += __shfl_down(s_prod, off);
        s_val += __shfl_down(s_val, off);
    }
    if (lane == 0) {
        const int base = (img < NB) ? 0 : 2;
        atomicAdd(&acc[base], (double)s_prod);
        atomicAdd(&acc[base + 1], (double)s_val);
    }
}

__global__ void finalize(const double* __restrict__ acc, float* __restrict__ out) {
    double tprec = (acc[0] + 1.0) / (acc[1] + 1.0);
    double tsens = (acc[2] + 1.0) / (acc[3] + 1.0);
    out[0] = (float)(1.0 - 2.0 * (tprec * tsens) / (tprec + tsens));
}

extern "C" void kernel_launch(void* const* d_in, const int* in_sizes, int n_in,
                              void* d_out, int out_size, void* d_ws, size_t ws_size,
                              hipStream_t stream) {
    (void)in_sizes; (void)n_in; (void)out_size; (void)ws_size;
    const float* yp = (const float*)d_in[0];
    const float* yt = (const float*)d_in[1];
    float* out = (float*)d_out;

    // Workspace: just the 4 reduction accumulators.
    double* acc = (double*)d_ws;
    hipMemsetAsync(acc, 0, 4 * sizeof(double), stream);

    const int grid = NIMG * NBAND;  // 2048 single-wave blocks = 2 waves/SIMD
    skel10<<<grid, 64, 0, stream>>>(yp, yt, acc);
    finalize<<<1, 1, 0, stream>>>(acc, out);
}

// Round 5
// 279.544 us; speedup vs baseline: 4.8090x; 4.8090x over previous
//
#include <hip/hip_runtime.h>

#define IMG 512
#define HW (IMG * IMG)
#define NB 32
#define NIMG 64
#define BAND 16
#define NBAND (IMG / BAND)              // 32
#define NSTG 5                          // fused iterations per launch
#define HALO (2 * NSTG)                 // 10
#define NSTEP ((BAND + 2 * HALO) / 2)   // 18 row-pair steps
#define INF __builtin_inff()

// DPP whole-wave shift-by-1 (CDNA keeps Vega wave_shl/shr DPP controls).
// wave_shr1: lane i gets lane i-1's value; lane 0 gets `ident`.
static __device__ __forceinline__ float dpp_from_prev(float v, float ident) {
    return __int_as_float(__builtin_amdgcn_update_dpp(
        __float_as_int(ident), __float_as_int(v), 0x138, 0xF, 0xF, false));
}
// wave_shl1: lane i gets lane i+1's value; lane 63 gets `ident`.
static __device__ __forceinline__ float dpp_from_next(float v, float ident) {
    return __int_as_float(__builtin_amdgcn_update_dpp(
        __float_as_int(ident), __float_as_int(v), 0x130, 0xF, 0xF, false));
}

// One lane owns 8 contiguous columns: a = cols[8l..8l+3], b = cols[8l+4..8l+7].
struct Row { float4 a, b; };

static __device__ __forceinline__ float min3f(float a, float b, float c) { return fminf(fminf(a, b), c); }
static __device__ __forceinline__ float max3f(float a, float b, float c) { return fmaxf(fmaxf(a, b), c); }

static __device__ __forceinline__ Row splat(float v) {
    Row r;
    r.a = make_float4(v, v, v, v);
    r.b = make_float4(v, v, v, v);
    return r;
}

static __device__ __forceinline__ Row rmin3(const Row& x, const Row& y, const Row& z) {
    Row o;
    const float* px = (const float*)&x;
    const float* py = (const float*)&y;
    const float* pz = (const float*)&z;
    float* po = (float*)&o;
#pragma unroll
    for (int i = 0; i < 8; ++i) po[i] = min3f(px[i], py[i], pz[i]);
    return o;
}

static __device__ __forceinline__ Row rmax3(const Row& x, const Row& y, const Row& z) {
    Row o;
    const float* px = (const float*)&x;
    const float* py = (const float*)&y;
    const float* pz = (const float*)&z;
    float* po = (float*)&o;
#pragma unroll
    for (int i = 0; i < 8; ++i) po[i] = max3f(px[i], py[i], pz[i]);
    return o;
}

// Horizontal 3-min across the 512-wide row. Lane-edge neighbors via DPP
// wave shifts; image edges get +inf identity for free from bound_ctrl.
static __device__ __forceinline__ Row hmin3(const Row& v) {
    float shl = dpp_from_prev(v.b.w, INF);
    float shr = dpp_from_next(v.a.x, INF);
    Row o;
    o.a.x = min3f(shl,   v.a.x, v.a.y);
    o.a.y = min3f(v.a.x, v.a.y, v.a.z);
    o.a.z = min3f(v.a.y, v.a.z, v.a.w);
    o.a.w = min3f(v.a.z, v.a.w, v.b.x);
    o.b.x = min3f(v.a.w, v.b.x, v.b.y);
    o.b.y = min3f(v.b.x, v.b.y, v.b.z);
    o.b.z = min3f(v.b.y, v.b.z, v.b.w);
    o.b.w = min3f(v.b.z, v.b.w, shr);
    return o;
}

static __device__ __forceinline__ Row hmax3(const Row& v) {
    float shl = dpp_from_prev(v.b.w, -INF);
    float shr = dpp_from_next(v.a.x, -INF);
    Row o;
    o.a.x = max3f(shl,   v.a.x, v.a.y);
    o.a.y = max3f(v.a.x, v.a.y, v.a.z);
    o.a.z = max3f(v.a.y, v.a.z, v.a.w);
    o.a.w = max3f(v.a.z, v.a.w, v.b.x);
    o.b.x = max3f(v.a.w, v.b.x, v.b.y);
    o.b.y = max3f(v.b.x, v.b.y, v.b.z);
    o.b.z = max3f(v.b.y, v.b.z, v.b.w);
    o.b.w = max3f(v.b.z, v.b.w, shr);
    return o;
}

// out = relu(x - relu(mp - mn)). For x >= 0 on every consumed output this is
// bit-exactly med3(0, x, x - (mp - mn)). Verified on-harness (absmax 0.0,
// rounds 2-4).
static __device__ __forceinline__ Row relu_out(const Row& x, const Row& mp, const Row& mn) {
    Row o;
    const float* px = (const float*)&x;
    const float* pp = (const float*)&mp;
    const float* pm = (const float*)&mn;
    float* po = (float*)&o;
#pragma unroll
    for (int i = 0; i < 8; ++i) {
        float d = pp[i] - pm[i];
        po[i] = __builtin_amdgcn_fmed3f(0.f, px[i], px[i] - d);
    }
    return o;
}

// BRANCH-FREE row load: always issues the load, row index clamped into the
// image. The old branchy load_or_inf (if OOB return splat) forced the
// compiler to resolve a WAW hazard between the splat-path mov and the
// in-flight load with a conservative s_waitcnt, collapsing the prefetch
// distance to ~0 (round-4 post-mortem: 96 us vs ~30 us issue floor, while
// spill traffic in round 4 proved 4.6 TB/s is available). OOB semantics are
// applied at CONSUME time by the caller (EDGE bands only).
static __device__ __forceinline__ Row load_row_clamped(const float* __restrict__ p,
                                                       int r, int lane) {
    const int rc = min(max(r, 0), IMG - 1);
    const float4* q = (const float4*)(p + (size_t)rc * IMG + lane * 8);
    Row o;
    o.a = q[0];
    o.b = q[1];
    return o;
}

// Row-paired skeletonize stage step (round-0 verified structure).
// Entry state: x[0]=x[t-2], x[1]=x[t-1], mn[0]=mn[t-3], mn[1]=mn[t-2].
// Inputs in0=x[t], in1=x[t+1]. On exit in0/in1 hold this stage's outputs for
// rows (t-2, t-1), state advanced by 2 rows.
template <bool EDGE>
static __device__ __forceinline__ void step2(Row (&x)[2], Row (&mn)[2],
                                             Row& in0, Row& in1, int t) {
    Row vmin0 = rmin3(x[0], x[1], in0);      // centered row t-1
    Row vmin1 = rmin3(x[1], in0, in1);       // centered row t
    Row mna = hmin3(vmin0);                  // mn[t-1]
    Row mnb = hmin3(vmin1);                  // mn[t]
    if (EDGE) {
        if ((unsigned)(t - 1) >= IMG) mna = splat(-INF);
        if ((unsigned)t >= IMG) mnb = splat(-INF);
    }
    Row vmax0 = rmax3(mn[0], mn[1], mna);    // centered t-2
    Row vmax1 = rmax3(mn[1], mna, mnb);      // centered t-1
    Row mp0 = hmax3(vmax0);
    Row mp1 = hmax3(vmax1);
    Row out0 = relu_out(x[0], mp0, mn[1]);   // out row t-2
    Row out1 = relu_out(x[1], mp1, mna);     // out row t-1
    if (EDGE) {
        if ((unsigned)(t - 2) >= IMG) out0 = splat(INF);
        if ((unsigned)(t - 1) >= IMG) out1 = splat(INF);
    }
    x[0] = in0;  x[1] = in1;
    mn[0] = mna; mn[1] = mnb;
    in0 = out0;  in1 = out1;
}

// Five fused iterations over one 16-row band. #pragma unroll 1 is deliberate
// (full unroll hoists all loads -> scratch spill, round-2 post-mortem).
// MODE 0: store final rows to dst. MODE 1: reduce against weights wp.
template <bool EDGE, int MODE>
static __device__ __forceinline__ void run(const float* __restrict__ src,
                                           float* __restrict__ dst,
                                           const float* __restrict__ wp,
                                           int B, int lane,
                                           float& s_prod, float& s_val) {
    Row x[NSTG][2], mn[NSTG][2];
#pragma unroll
    for (int j = 0; j < NSTG; ++j) {
        x[j][0] = splat(INF);   x[j][1] = splat(INF);
        mn[j][0] = splat(-INF); mn[j][1] = splat(-INF);
    }
    Row pre0 = load_row_clamped(src, B - HALO, lane);
    Row pre1 = load_row_clamped(src, B - HALO + 1, lane);
#pragma unroll 1
    for (int k = 0; k < NSTEP; ++k) {
        const int t = B - HALO + 2 * k;
        Row in0 = pre0, in1 = pre1;
        // consume-time OOB override (uniform scalar branch; EDGE bands only —
        // with HALO=10 < BAND=16 only bands 0 and 31 touch out-of-image rows)
        if (EDGE) {
            if ((unsigned)t >= IMG) in0 = splat(INF);
            if ((unsigned)(t + 1) >= IMG) in1 = splat(INF);
        }
        // prefetch next row pair — unconditional, stays in flight across the
        // whole 5-stage chain (~1850 cycles >> HBM latency)
        pre0 = load_row_clamped(src, t + 2, lane);
        pre1 = load_row_clamped(src, t + 3, lane);
        const int v = t - HALO;              // final-stage out row pair (v, v+1)
        const bool inband = (unsigned)(v - B) < BAND;
        // MODE 1: weight loads also unconditional + clamped; accumulation
        // below remains guarded. Values consumed only when inband.
        Row w0, w1;
        if (MODE == 1) {
            w0 = load_row_clamped(wp, v, lane);
            w1 = load_row_clamped(wp, v + 1, lane);
        }
#pragma unroll
        for (int j = 0; j < NSTG; ++j)
            step2<EDGE>(x[j], mn[j], in0, in1, t - 2 * j);
        if (inband) {
            if (MODE == 0) {
                float4* q0 = (float4*)(dst + (size_t)v * IMG + lane * 8);
                q0[0] = in0.a; q0[1] = in0.b;
                float4* q1 = (float4*)(dst + (size_t)(v + 1) * IMG + lane * 8);
                q1[0] = in1.a; q1[1] = in1.b;
            } else {
                const float* p0 = (const float*)&in0;
                const float* p1 = (const float*)&in1;
                const float* q0 = (const float*)&w0;
                const float* q1 = (const float*)&w1;
#pragma unroll
                for (int i = 0; i < 8; ++i) {
                    s_prod += p0[i] * q0[i] + p1[i] * q1[i];
                    s_val += p0[i] + p1[i];
                }
            }
        }
    }
}

// ---------------- Launch 1: iterations 0..4, write intermediate ----------------
__global__ __launch_bounds__(64, 2) void skel5_a(const float* __restrict__ yp,
                                                 const float* __restrict__ yt,
                                                 float* __restrict__ mid) {
    const int blk = blockIdx.x;
    const int img = blk >> 5, band = blk & (NBAND - 1);
    const float* src = (img < NB) ? yp + (size_t)(2 * img + 1) * HW
                                  : yt + (size_t)(2 * (img - NB) + 1) * HW;
    float* dst = mid + (size_t)img * HW;
    const int lane = threadIdx.x;
    const int B = band * BAND;
    float d0 = 0.f, d1 = 0.f;
    if (band == 0 || band == NBAND - 1) run<true, 0>(src, dst, nullptr, B, lane, d0, d1);
    else                                run<false, 0>(src, dst, nullptr, B, lane, d0, d1);
}

// ---------- Launch 2: iterations 5..9 + fused reduction (no write-out) ----------
__global__ __launch_bounds__(64, 2) void skel5_b(const float* __restrict__ mid,
                                                 const float* __restrict__ yp,
                                                 const float* __restrict__ yt,
                                                 double* __restrict__ acc) {
    const int blk = blockIdx.x;
    const int img = blk >> 5, band = blk & (NBAND - 1);
    const float* src = mid + (size_t)img * HW;
    // skel(pred) pairs with y_true c1; skel(true) pairs with y_pred c1.
    const float* wp = (img < NB) ? yt + (size_t)(2 * img + 1) * HW
                                 : yp + (size_t)(2 * (img - NB) + 1) * HW;
    const int lane = threadIdx.x;
    const int B = band * BAND;

    float s_prod = 0.f, s_val = 0.f;
    if (band == 0 || band == NBAND - 1) run<true, 1>(src, nullptr, wp, B, lane, s_prod, s_val);
    else                                run<false, 1>(src, nullptr, wp, B, lane, s_prod, s_val);

#pragma unroll
    for (int off = 32; off; off >>= 1) {
        s_prod += __shfl_down(s_prod, off);
        s_val += __shfl_down(s_val, off);
    }
    if (lane == 0) {
        const int base = (img < NB) ? 0 : 2;
        atomicAdd(&acc[base], (double)s_prod);
        atomicAdd(&acc[base + 1], (double)s_val);
    }
}

__global__ void finalize(const double* __restrict__ acc, float* __restrict__ out) {
    double tprec = (acc[0] + 1.0) / (acc[1] + 1.0);
    double tsens = (acc[2] + 1.0) / (acc[3] + 1.0);
    out[0] = (float)(1.0 - 2.0 * (tprec * tsens) / (tprec + tsens));
}

extern "C" void kernel_launch(void* const* d_in, const int* in_sizes, int n_in,
                              void* d_out, int out_size, void* d_ws, size_t ws_size,
                              hipStream_t stream) {
    (void)in_sizes; (void)n_in; (void)out_size; (void)ws_size;
    const float* yp = (const float*)d_in[0];
    const float* yt = (const float*)d_in[1];
    float* out = (float*)d_out;

    // Workspace: intermediate skeleton-after-5-iters (64 MB) | acc (4 doubles)
    float* mid = (float*)d_ws;
    double* acc = (double*)(mid + (size_t)NIMG * HW);

    hipMemsetAsync(acc, 0, 4 * sizeof(double), stream);

    const int grid = NIMG * NBAND;  // 2048 single-wave blocks = 2 waves/SIMD
    skel5_a<<<grid, 64, 0, stream>>>(yp, yt, mid);
    skel5_b<<<grid, 64, 0, stream>>>(mid, yp, yt, acc);
    finalize<<<1, 1, 0, stream>>>(acc, out);
}

// Round 6
// 277.478 us; speedup vs baseline: 4.8448x; 1.0074x over previous
//
#include <hip/hip_runtime.h>

#define IMG 512
#define HW (IMG * IMG)
#define NB 32
#define NIMG 64
#define BAND 16
#define NBAND (IMG / BAND)              // 32
#define NSTG 5                          // fused iterations per launch
#define HALO (2 * NSTG)                 // 10
#define NSTEP ((BAND + 2 * HALO) / 2)   // 18 row-pair steps
#define INF __builtin_inff()

// DPP whole-wave shift-by-1 (CDNA keeps Vega wave_shl/shr DPP controls).
// wave_shr1: lane i gets lane i-1's value; lane 0 gets `ident`.
static __device__ __forceinline__ float dpp_from_prev(float v, float ident) {
    return __int_as_float(__builtin_amdgcn_update_dpp(
        __float_as_int(ident), __float_as_int(v), 0x138, 0xF, 0xF, false));
}
// wave_shl1: lane i gets lane i+1's value; lane 63 gets `ident`.
static __device__ __forceinline__ float dpp_from_next(float v, float ident) {
    return __int_as_float(__builtin_amdgcn_update_dpp(
        __float_as_int(ident), __float_as_int(v), 0x130, 0xF, 0xF, false));
}

// One lane owns 8 contiguous columns: a = cols[8l..8l+3], b = cols[8l+4..8l+7].
struct Row { float4 a, b; };

static __device__ __forceinline__ float min3f(float a, float b, float c) { return fminf(fminf(a, b), c); }
static __device__ __forceinline__ float max3f(float a, float b, float c) { return fmaxf(fmaxf(a, b), c); }

static __device__ __forceinline__ Row splat(float v) {
    Row r;
    r.a = make_float4(v, v, v, v);
    r.b = make_float4(v, v, v, v);
    return r;
}

static __device__ __forceinline__ Row rmin3(const Row& x, const Row& y, const Row& z) {
    Row o;
    const float* px = (const float*)&x;
    const float* py = (const float*)&y;
    const float* pz = (const float*)&z;
    float* po = (float*)&o;
#pragma unroll
    for (int i = 0; i < 8; ++i) po[i] = min3f(px[i], py[i], pz[i]);
    return o;
}

static __device__ __forceinline__ Row rmax3(const Row& x, const Row& y, const Row& z) {
    Row o;
    const float* px = (const float*)&x;
    const float* py = (const float*)&y;
    const float* pz = (const float*)&z;
    float* po = (float*)&o;
#pragma unroll
    for (int i = 0; i < 8; ++i) po[i] = max3f(px[i], py[i], pz[i]);
    return o;
}

// Horizontal 3-min across the 512-wide row. Lane-edge neighbors via DPP
// wave shifts; image edges get +inf identity for free from bound_ctrl.
static __device__ __forceinline__ Row hmin3(const Row& v) {
    float shl = dpp_from_prev(v.b.w, INF);
    float shr = dpp_from_next(v.a.x, INF);
    Row o;
    o.a.x = min3f(shl,   v.a.x, v.a.y);
    o.a.y = min3f(v.a.x, v.a.y, v.a.z);
    o.a.z = min3f(v.a.y, v.a.z, v.a.w);
    o.a.w = min3f(v.a.z, v.a.w, v.b.x);
    o.b.x = min3f(v.a.w, v.b.x, v.b.y);
    o.b.y = min3f(v.b.x, v.b.y, v.b.z);
    o.b.z = min3f(v.b.y, v.b.z, v.b.w);
    o.b.w = min3f(v.b.z, v.b.w, shr);
    return o;
}

static __device__ __forceinline__ Row hmax3(const Row& v) {
    float shl = dpp_from_prev(v.b.w, -INF);
    float shr = dpp_from_next(v.a.x, -INF);
    Row o;
    o.a.x = max3f(shl,   v.a.x, v.a.y);
    o.a.y = max3f(v.a.x, v.a.y, v.a.z);
    o.a.z = max3f(v.a.y, v.a.z, v.a.w);
    o.a.w = max3f(v.a.z, v.a.w, v.b.x);
    o.b.x = max3f(v.a.w, v.b.x, v.b.y);
    o.b.y = max3f(v.b.x, v.b.y, v.b.z);
    o.b.z = max3f(v.b.y, v.b.z, v.b.w);
    o.b.w = max3f(v.b.z, v.b.w, shr);
    return o;
}

// out = relu(x - relu(mp - mn)). For x >= 0 on every consumed output this is
// bit-exactly med3(0, x, x - (mp - mn)). Verified on-harness (absmax 0.0,
// rounds 2-5).
static __device__ __forceinline__ Row relu_out(const Row& x, const Row& mp, const Row& mn) {
    Row o;
    const float* px = (const float*)&x;
    const float* pp = (const float*)&mp;
    const float* pm = (const float*)&mn;
    float* po = (float*)&o;
#pragma unroll
    for (int i = 0; i < 8; ++i) {
        float d = pp[i] - pm[i];
        po[i] = __builtin_amdgcn_fmed3f(0.f, px[i], px[i] - d);
    }
    return o;
}

// BRANCH-FREE row load: always issues the load, row index clamped into the
// image. A load under a (even uniform) branch makes the outstanding-vmcnt
// count path-dependent at the merge, forcing the compiler to emit a
// conservative s_waitcnt vmcnt(0) that drains the just-issued prefetch and
// serializes every k-step. Branch-free loads keep the count static so the
// compiler can use counted vmcnt(N) and the prefetch spans the whole stage
// chain. OOB semantics are applied at CONSUME time by the caller.
static __device__ __forceinline__ Row load_row_clamped(const float* __restrict__ p,
                                                       int r, int lane) {
    const int rc = min(max(r, 0), IMG - 1);
    const float4* q = (const float4*)(p + (size_t)rc * IMG + lane * 8);
    Row o;
    o.a = q[0];
    o.b = q[1];
    return o;
}

// Row-paired skeletonize stage step (round-0 verified structure).
// Entry state: x[0]=x[t-2], x[1]=x[t-1], mn[0]=mn[t-3], mn[1]=mn[t-2].
// Inputs in0=x[t], in1=x[t+1]. On exit in0/in1 hold this stage's outputs for
// rows (t-2, t-1), state advanced by 2 rows.
template <bool EDGE>
static __device__ __forceinline__ void step2(Row (&x)[2], Row (&mn)[2],
                                             Row& in0, Row& in1, int t) {
    Row vmin0 = rmin3(x[0], x[1], in0);      // centered row t-1
    Row vmin1 = rmin3(x[1], in0, in1);       // centered row t
    Row mna = hmin3(vmin0);                  // mn[t-1]
    Row mnb = hmin3(vmin1);                  // mn[t]
    if (EDGE) {
        if ((unsigned)(t - 1) >= IMG) mna = splat(-INF);
        if ((unsigned)t >= IMG) mnb = splat(-INF);
    }
    Row vmax0 = rmax3(mn[0], mn[1], mna);    // centered t-2
    Row vmax1 = rmax3(mn[1], mna, mnb);      // centered t-1
    Row mp0 = hmax3(vmax0);
    Row mp1 = hmax3(vmax1);
    Row out0 = relu_out(x[0], mp0, mn[1]);   // out row t-2
    Row out1 = relu_out(x[1], mp1, mna);     // out row t-1
    if (EDGE) {
        if ((unsigned)(t - 2) >= IMG) out0 = splat(INF);
        if ((unsigned)(t - 1) >= IMG) out1 = splat(INF);
    }
    x[0] = in0;  x[1] = in1;
    mn[0] = mna; mn[1] = mnb;
    in0 = out0;  in1 = out1;
}

// Five fused iterations over one 16-row band. #pragma unroll 1 is deliberate
// (full unroll hoists all loads -> scratch spill, round-2 post-mortem).
// All loads are branch-free (static vmcnt counts); loop body issues the next
// prefetch FIRST, then consumes the previous one under the chain.
// MODE 0: store final rows to dst. MODE 1: reduce against weights wp
// (weight loads unconditional too — an inband-guarded weight load would force
// vmcnt(0) at its consume point, draining the row prefetch with it).
template <bool EDGE, int MODE>
static __device__ __forceinline__ void run(const float* __restrict__ src,
                                           float* __restrict__ dst,
                                           const float* __restrict__ wp,
                                           int B, int lane,
                                           float& s_prod, float& s_val) {
    Row x[NSTG][2], mn[NSTG][2];
#pragma unroll
    for (int j = 0; j < NSTG; ++j) {
        x[j][0] = splat(INF);   x[j][1] = splat(INF);
        mn[j][0] = splat(-INF); mn[j][1] = splat(-INF);
    }
    Row pre0 = load_row_clamped(src, B - HALO, lane);
    Row pre1 = load_row_clamped(src, B - HALO + 1, lane);
#pragma unroll 1
    for (int k = 0; k < NSTEP; ++k) {
        const int t = B - HALO + 2 * k;
        const int v = t - HALO;              // final-stage out row pair (v, v+1)
        // 1) issue next-step prefetch into fresh temps — stays in flight
        //    across the whole 5-stage chain (~12k cycles >> HBM latency)
        Row nxt0 = load_row_clamped(src, t + 2, lane);
        Row nxt1 = load_row_clamped(src, t + 3, lane);
        // 2) issue weight loads (MODE 1), also unconditional
        Row w0, w1;
        if (MODE == 1) {
            w0 = load_row_clamped(wp, v, lane);
            w1 = load_row_clamped(wp, v + 1, lane);
        }
        // 3) consume the previous prefetch (counted vmcnt leaves nxt/w flying)
        Row in0 = pre0, in1 = pre1;
        if (EDGE) {
            // consume-time OOB override (uniform scalar branch; with HALO=10
            // < BAND=16 only bands 0 and 31 touch out-of-image rows)
            if ((unsigned)t >= IMG) in0 = splat(INF);
            if ((unsigned)(t + 1) >= IMG) in1 = splat(INF);
        }
#pragma unroll
        for (int j = 0; j < NSTG; ++j)
            step2<EDGE>(x[j], mn[j], in0, in1, t - 2 * j);
        const bool inband = (unsigned)(v - B) < BAND;
        if (inband) {
            if (MODE == 0) {
                float4* q0 = (float4*)(dst + (size_t)v * IMG + lane * 8);
                q0[0] = in0.a; q0[1] = in0.b;
                float4* q1 = (float4*)(dst + (size_t)(v + 1) * IMG + lane * 8);
                q1[0] = in1.a; q1[1] = in1.b;
            } else {
                const float* p0 = (const float*)&in0;
                const float* p1 = (const float*)&in1;
                const float* q0 = (const float*)&w0;
                const float* q1 = (const float*)&w1;
#pragma unroll
                for (int i = 0; i < 8; ++i) {
                    s_prod += p0[i] * q0[i] + p1[i] * q1[i];
                    s_val += p0[i] + p1[i];
                }
            }
        }
        // 4) rotate prefetch
        pre0 = nxt0;
        pre1 = nxt1;
    }
}

// __launch_bounds__(64, 1): empirically hipcc budgets VGPR cap = 256/min_waves
// and SPILLS past it rather than allocating more ((64,4)->64+spill r2,
// (64,2)->128+spill r4/r5). Our grid (2048 blocks) only sustains 2 waves/SIMD
// anyway, and any VGPR count <= 256 still permits that — so min_waves=1 frees
// the allocator at zero occupancy cost.
__global__ __launch_bounds__(64, 1) void skel5_a(const float* __restrict__ yp,
                                                 const float* __restrict__ yt,
                                                 float* __restrict__ mid) {
    const int blk = blockIdx.x;
    const int img = blk >> 5, band = blk & (NBAND - 1);
    const float* src = (img < NB) ? yp + (size_t)(2 * img + 1) * HW
                                  : yt + (size_t)(2 * (img - NB) + 1) * HW;
    float* dst = mid + (size_t)img * HW;
    const int lane = threadIdx.x;
    const int B = band * BAND;
    float d0 = 0.f, d1 = 0.f;
    if (band == 0 || band == NBAND - 1) run<true, 0>(src, dst, nullptr, B, lane, d0, d1);
    else                                run<false, 0>(src, dst, nullptr, B, lane, d0, d1);
}

__global__ __launch_bounds__(64, 1) void skel5_b(const float* __restrict__ mid,
                                                 const float* __restrict__ yp,
                                                 const float* __restrict__ yt,
                                                 double* __restrict__ acc) {
    const int blk = blockIdx.x;
    const int img = blk >> 5, band = blk & (NBAND - 1);
    const float* src = mid + (size_t)img * HW;
    // skel(pred) pairs with y_true c1; skel(true) pairs with y_pred c1.
    const float* wp = (img < NB) ? yt + (size_t)(2 * img + 1) * HW
                                 : yp + (size_t)(2 * (img - NB) + 1) * HW;
    const int lane = threadIdx.x;
    const int B = band * BAND;

    float s_prod = 0.f, s_val = 0.f;
    if (band == 0 || band == NBAND - 1) run<true, 1>(src, nullptr, wp, B, lane, s_prod, s_val);
    else                                run<false, 1>(src, nullptr, wp, B, lane, s_prod, s_val);

#pragma unroll
    for (int off = 32; off; off >>= 1) {
        s_prod += __shfl_down(s_prod, off);
        s_val += __shfl_down(s_val, off);
    }
    if (lane == 0) {
        const int base = (img < NB) ? 0 : 2;
        atomicAdd(&acc[base], (double)s_prod);
        atomicAdd(&acc[base + 1], (double)s_val);
    }
}

__global__ void finalize(const double* __restrict__ acc, float* __restrict__ out) {
    double tprec = (acc[0] + 1.0) / (acc[1] + 1.0);
    double tsens = (acc[2] + 1.0) / (acc[3] + 1.0);
    out[0] = (float)(1.0 - 2.0 * (tprec * tsens) / (tprec + tsens));
}

extern "C" void kernel_launch(void* const* d_in, const int* in_sizes, int n_in,
                              void* d_out, int out_size, void* d_ws, size_t ws_size,
                              hipStream_t stream) {
    (void)in_sizes; (void)n_in; (void)out_size; (void)ws_size;
    const float* yp = (const float*)d_in[0];
    const float* yt = (const float*)d_in[1];
    float* out = (float*)d_out;

    // Workspace: intermediate skeleton-after-5-iters (64 MB) | acc (4 doubles)
    float* mid = (float*)d_ws;
    double* acc = (double*)(mid + (size_t)NIMG * HW);

    hipMemsetAsync(acc, 0, 4 * sizeof(double), stream);

    const int grid = NIMG * NBAND;  // 2048 single-wave blocks = 2 waves/SIMD
    skel5_a<<<grid, 64, 0, stream>>>(yp, yt, mid);
    skel5_b<<<grid, 64, 0, stream>>>(mid, yp, yt, acc);
    finalize<<<1, 1, 0, stream>>>(acc, out);
}